// Round 6
// baseline (23.275 us; speedup 1.0000x reference)
//
#include <hip/hip_runtime.h>
#include <math.h>

// StridedAttention, single-barrier form: K/Q direct global->reg (no staging phase),
// softmax + P fully in-register; LDS holds only V^T.
// B=1, H=16, S=2048, D=64, window ±16 (33 local), stride 32 (64 strided)

typedef __attribute__((ext_vector_type(8))) short bf16x8;   // 8 bf16 = 4 VGPR
typedef __attribute__((ext_vector_type(4))) float f32x4;

constexpr int H = 16, S = 2048, D = 64, W = 16;
constexpr int QB   = 64;      // queries per block
constexpr int NLOC = 96;      // local union rows (QB + 2W)
constexpr int NT   = 10;      // key tiles of 16 (96 local + 64 strided)
constexpr float S2 = 0.18033688011112042f;   // 0.125 * log2(e); softmax in exp2 domain

constexpr int VSTR  = 168;            // V^T row stride in ushorts (160 slots + 8 pad)
constexpr int LDS_U = D * VSTR;       // 10752 ushorts = 21504 B

__device__ __forceinline__ ushort f2bf(float x) {
    union { float f; unsigned u; } t; t.f = x;
    unsigned r = t.u + 0x7fffu + ((t.u >> 16) & 1u);   // RNE
    return (ushort)(r >> 16);
}
__device__ __forceinline__ float bf2f(ushort b) {
    union { float f; unsigned u; } t; t.u = ((unsigned)b) << 16;
    return t.f;
}
__device__ __forceinline__ unsigned pk2(float a, float b) {
    return (unsigned)f2bf(a) | ((unsigned)f2bf(b) << 16);
}
__device__ __forceinline__ bf16x8 cvt8(const float4& a, const float4& b) {
    union { bf16x8 v; unsigned u[4]; } r;
    r.u[0] = pk2(a.x, a.y); r.u[1] = pk2(a.z, a.w);
    r.u[2] = pk2(b.x, b.y); r.u[3] = pk2(b.z, b.w);
    return r.v;
}
__device__ __forceinline__ void cvt_hilo(const float4& a, const float4& b,
                                         bf16x8& hi, bf16x8& lo) {
    const float xs[8] = {a.x, a.y, a.z, a.w, b.x, b.y, b.z, b.w};
    union { bf16x8 v; ushort u[8]; } Hv, Lv;
#pragma unroll
    for (int j = 0; j < 8; ++j) {
        const ushort hb = f2bf(xs[j]);
        Hv.u[j] = hb;
        Lv.u[j] = f2bf(xs[j] - bf2f(hb));
    }
    hi = Hv.v; lo = Lv.v;
}
__device__ __forceinline__ int rowpos(int r, int n0) {
    if (r < NLOC) {
        int p = n0 - W + r;               // clamped rows masked in softmax
        return p < 0 ? 0 : (p > S - 1 ? S - 1 : p);
    }
    return (r - NLOC) * 32;               // strided keys
}

__global__ __launch_bounds__(256, 2) void strided_attn_mfma(
    const float* __restrict__ q,
    const float* __restrict__ k,
    const float* __restrict__ v,
    float* __restrict__ out)
{
    __shared__ ushort lds[LDS_U];         // V^T [64 dims][168]

    const int tid  = threadIdx.x;
    const int w    = tid >> 6;
    const int lane = tid & 63;
    const int c    = lane & 15;           // query column within wave's 16
    const int g    = lane >> 4;           // k-chunk
    // XCD-aware bijective swizzle (512 % 8 == 0): 2 heads per XCD -> K/V L2-resident
    const int bid  = blockIdx.x;
    const int swz  = (bid & 7) * 64 + (bid >> 3);
    const int h    = swz >> 5;
    const int n0   = (swz & 31) << 6;

    const float* __restrict__ qh = q + (size_t)(h * S) * D;
    const float* __restrict__ kh = k + (size_t)(h * S) * D;
    const float* __restrict__ vh = v + (size_t)(h * S) * D;

    // ---- V prefetch into regs (issue-early). 640 tasks: 2 rows x 8 dims each.
    const int ntask = (tid < 128) ? 3 : 2;
    float4 vreg[3][4];
#pragma unroll
    for (int tt = 0; tt < 3; ++tt) {
        if (tt < ntask) {
            const int tau = tid + (tt << 8);
            const int rp = tau % 80, ch = tau / 80;
            const float* s0 = vh + (size_t)rowpos(2 * rp,     n0) * D + ch * 8;
            const float* s1 = vh + (size_t)rowpos(2 * rp + 1, n0) * D + ch * 8;
            vreg[tt][0] = *(const float4*)s0;
            vreg[tt][1] = *(const float4*)(s0 + 4);
            vreg[tt][2] = *(const float4*)s1;
            vreg[tt][3] = *(const float4*)(s1 + 4);
        }
    }

    // ---- Q direct load + hi/lo convert (B-operand frags; lane c = query qb+c) ----
    const int qb = w * 16;
    const int qi = qb + c;                // this lane's block-relative query
    const int nq = n0 + qi;
    const float* qrow = qh + (size_t)(n0 + qb + c) * D;
    const float4 qv00 = *(const float4*)(qrow + g * 8);
    const float4 qv01 = *(const float4*)(qrow + g * 8 + 4);
    const float4 qv10 = *(const float4*)(qrow + 32 + g * 8);
    const float4 qv11 = *(const float4*)(qrow + 32 + g * 8 + 4);
    bf16x8 bQH0, bQL0, bQH1, bQL1;
    cvt_hilo(qv00, qv01, bQH0, bQL0);
    cvt_hilo(qv10, qv11, bQH1, bQL1);

    // ---- QK^T swapped (S^T = K·Q^T), K straight from global with in-lane convert.
    // A-frag for tile t: K row 16t+c, dims [g*8,g*8+8) (a0) and [32+g*8,..) (a1).
    f32x4 acc[NT];
#pragma unroll
    for (int t = 0; t < NT; ++t) acc[t] = (f32x4){0.f, 0.f, 0.f, 0.f};

#pragma unroll
    for (int t = 0; t < NT; ++t) {
        int pos;
        if (t < 6) {                                  // local rows j = 16t+c < 96
            const int p = n0 - W + 16 * t + c;
            pos = p < 0 ? 0 : (p > S - 1 ? S - 1 : p);
        } else {                                      // strided rows
            pos = (16 * (t - 6) + c) * 32;
        }
        const float* kr = kh + (size_t)pos * D;
        const float4 k00 = *(const float4*)(kr + g * 8);
        const float4 k01 = *(const float4*)(kr + g * 8 + 4);
        const float4 k10 = *(const float4*)(kr + 32 + g * 8);
        const float4 k11 = *(const float4*)(kr + 32 + g * 8 + 4);
        const bf16x8 a0 = cvt8(k00, k01);
        const bf16x8 a1 = cvt8(k10, k11);
        f32x4 a4 = acc[t];
        a4 = __builtin_amdgcn_mfma_f32_16x16x32_bf16(a0, bQH0, a4, 0, 0, 0);
        a4 = __builtin_amdgcn_mfma_f32_16x16x32_bf16(a1, bQH1, a4, 0, 0, 0);
        a4 = __builtin_amdgcn_mfma_f32_16x16x32_bf16(a0, bQL0, a4, 0, 0, 0);
        a4 = __builtin_amdgcn_mfma_f32_16x16x32_bf16(a1, bQL1, a4, 0, 0, 0);
        acc[t] = a4;
    }

    // ---- pack V to bf16 pairs (loads long since arrived) and write V^T ----
    unsigned vpk[3][8];
#pragma unroll
    for (int tt = 0; tt < 3; ++tt) {
        if (tt < ntask) {
            const float r0[8] = {vreg[tt][0].x, vreg[tt][0].y, vreg[tt][0].z, vreg[tt][0].w,
                                 vreg[tt][1].x, vreg[tt][1].y, vreg[tt][1].z, vreg[tt][1].w};
            const float r1[8] = {vreg[tt][2].x, vreg[tt][2].y, vreg[tt][2].z, vreg[tt][2].w,
                                 vreg[tt][3].x, vreg[tt][3].y, vreg[tt][3].z, vreg[tt][3].w};
#pragma unroll
            for (int j = 0; j < 8; ++j) vpk[tt][j] = pk2(r0[j], r1[j]);
        }
    }
    // key 32kt+16u+4g2+jj -> slot 32kt+8g2+4u+jj (same k-permutation as pa pack)
#pragma unroll
    for (int tt = 0; tt < 3; ++tt) {
        if (tt < ntask) {
            const int tau = tid + (tt << 8);
            const int rp = tau % 80, ch = tau / 80;
            const int kk = 2 * rp;
            const int kt = kk >> 5, rem = kk & 31;
            const int slot = kt * 32 + ((rem >> 2) & 3) * 8 + (rem >> 4) * 4 + (rem & 3);
#pragma unroll
            for (int j = 0; j < 8; ++j)
                *(unsigned*)&lds[(ch * 8 + j) * VSTR + slot] = vpk[tt][j];
        }
    }

    // ---- softmax fully in-lane (exp2 domain): lane holds keys {16t+4g+i} of query qi
    float p[NT][4];
#pragma unroll
    for (int t = 0; t < 6; ++t) {
#pragma unroll
        for (int i = 0; i < 4; ++i) {
            const int j = t * 16 + 4 * g + i;
            const bool ok = ((unsigned)(j - qi) <= 32u) &&
                            ((unsigned)(n0 - W + j) < (unsigned)S);
            p[t][i] = ok ? acc[t][i] * S2 : -INFINITY;
        }
    }
    const bool us = nq > W;
#pragma unroll
    for (int t = 6; t < NT; ++t)
#pragma unroll
        for (int i = 0; i < 4; ++i)
            p[t][i] = us ? acc[t][i] * S2 : -INFINITY;

    float m = -INFINITY;
#pragma unroll
    for (int t = 0; t < NT; ++t)
#pragma unroll
        for (int i = 0; i < 4; ++i) m = fmaxf(m, p[t][i]);
    m = fmaxf(m, __shfl_xor(m, 16));
    m = fmaxf(m, __shfl_xor(m, 32));     // finite: self-key always valid

    float l = 0.f;
#pragma unroll
    for (int t = 0; t < NT; ++t)
#pragma unroll
        for (int i = 0; i < 4; ++i) { p[t][i] = exp2f(p[t][i] - m); l += p[t][i]; }
    l += __shfl_xor(l, 16);
    l += __shfl_xor(l, 32);
    const float inv = 1.0f / l;

    // ---- pack P into PV A-frags in-register (k-permutation shared with V^T) ----
    union { bf16x8 v; unsigned u[4]; } pa[5];
#pragma unroll
    for (int kt = 0; kt < 5; ++kt) {
        pa[kt].u[0] = pk2(p[2 * kt][0] * inv,     p[2 * kt][1] * inv);
        pa[kt].u[1] = pk2(p[2 * kt][2] * inv,     p[2 * kt][3] * inv);
        pa[kt].u[2] = pk2(p[2 * kt + 1][0] * inv, p[2 * kt + 1][1] * inv);
        pa[kt].u[3] = pk2(p[2 * kt + 1][2] * inv, p[2 * kt + 1][3] * inv);
    }

    __syncthreads();   // the ONLY barrier: all V^T writes visible

    // ---- PV: o[q][d] = P(16x160) x V(160x64); A = pa (in-reg), B = V^T (LDS) ----
    f32x4 o[4];
#pragma unroll
    for (int dt = 0; dt < 4; ++dt) o[dt] = (f32x4){0.f, 0.f, 0.f, 0.f};
#pragma unroll
    for (int kt = 0; kt < 5; ++kt) {
#pragma unroll
        for (int dt = 0; dt < 4; ++dt) {
            const bf16x8 vb = *(bf16x8*)&lds[(dt * 16 + c) * VSTR + kt * 32 + g * 8];
            o[dt] = __builtin_amdgcn_mfma_f32_16x16x32_bf16(pa[kt].v, vb, o[dt], 0, 0, 0);
        }
    }

    // ---- store (D row = query qb+4g+i, col c = dim within tile; P pre-normalized)
#pragma unroll
    for (int i = 0; i < 4; ++i) {
        const int n = n0 + qb + 4 * g + i;
        float* op = out + ((size_t)(h * S) + n) * D + c;
#pragma unroll
        for (int dt = 0; dt < 4; ++dt) op[dt * 16] = o[dt][i];
    }
}

extern "C" void kernel_launch(void* const* d_in, const int* in_sizes, int n_in,
                              void* d_out, int out_size, void* d_ws, size_t ws_size,
                              hipStream_t stream) {
    (void)in_sizes; (void)n_in; (void)d_ws; (void)ws_size; (void)out_size;
    const float* q = (const float*)d_in[0];
    const float* k = (const float*)d_in[1];
    const float* v = (const float*)d_in[2];
    float* out     = (float*)d_out;

    dim3 grid(H * (S / QB));   // 512 blocks
    dim3 block(256);
    strided_attn_mfma<<<grid, block, 0, stream>>>(q, k, v, out);
}

// Round 7
// 16.372 us; speedup vs baseline: 1.4217x; 1.4217x over previous
//
#include <hip/hip_runtime.h>
#include <math.h>

// StridedAttention, single-barrier hybrid: K staged in LDS (coalesced), Q direct
// global->reg (hi/lo), V^T in dedicated LDS region written pre-barrier,
// softmax + P fully in-register (swapped-QK MFMA form).
// B=1, H=16, S=2048, D=64, window ±16 (33 local), stride 32 (64 strided)

typedef __attribute__((ext_vector_type(8))) short bf16x8;   // 8 bf16 = 4 VGPR
typedef __attribute__((ext_vector_type(4))) float f32x4;

constexpr int H = 16, S = 2048, D = 64, W = 16;
constexpr int QB   = 64;      // queries per block
constexpr int NLOC = 96;      // local union rows (QB + 2W)
constexpr int NROWS = 160;    // 96 local + 64 strided
constexpr int NT   = 10;      // key tiles of 16
constexpr float S2 = 0.18033688011112042f;   // 0.125 * log2(e); exp2-domain softmax

// LDS (ushort units)
constexpr int KSTRIDE = 72;               // K row: 64 bf16 + 8 pad (144 B)
constexpr int VSTR    = 168;              // V^T row: 160 slots + 8 pad (336 B)
constexpr int KB      = 0;                // K bf16 [160][72]
constexpr int VTB     = NROWS * KSTRIDE;  // 11520: V^T [64][168]
constexpr int LDS_U   = VTB + D * VSTR;   // 22272 ushort = 44544 B

__device__ __forceinline__ ushort f2bf(float x) {
    union { float f; unsigned u; } t; t.f = x;
    unsigned r = t.u + 0x7fffu + ((t.u >> 16) & 1u);   // RNE
    return (ushort)(r >> 16);
}
__device__ __forceinline__ float bf2f(ushort b) {
    union { float f; unsigned u; } t; t.u = ((unsigned)b) << 16;
    return t.f;
}
__device__ __forceinline__ unsigned pk2(float a, float b) {
    return (unsigned)f2bf(a) | ((unsigned)f2bf(b) << 16);
}
__device__ __forceinline__ bf16x8 cvt8(const float4& a, const float4& b) {
    union { bf16x8 v; unsigned u[4]; } r;
    r.u[0] = pk2(a.x, a.y); r.u[1] = pk2(a.z, a.w);
    r.u[2] = pk2(b.x, b.y); r.u[3] = pk2(b.z, b.w);
    return r.v;
}
__device__ __forceinline__ void cvt_hilo(const float4& a, const float4& b,
                                         bf16x8& hi, bf16x8& lo) {
    const float xs[8] = {a.x, a.y, a.z, a.w, b.x, b.y, b.z, b.w};
    union { bf16x8 v; ushort u[8]; } Hv, Lv;
#pragma unroll
    for (int j = 0; j < 8; ++j) {
        const ushort hb = f2bf(xs[j]);
        Hv.u[j] = hb;
        Lv.u[j] = f2bf(xs[j] - bf2f(hb));
    }
    hi = Hv.v; lo = Lv.v;
}
__device__ __forceinline__ int rowpos(int r, int n0) {
    if (r < NLOC) {
        int p = n0 - W + r;               // clamped rows masked in softmax
        return p < 0 ? 0 : (p > S - 1 ? S - 1 : p);
    }
    return (r - NLOC) * 32;               // strided keys
}

__global__ __launch_bounds__(256, 2) void strided_attn_mfma(
    const float* __restrict__ q,
    const float* __restrict__ k,
    const float* __restrict__ v,
    float* __restrict__ out)
{
    __shared__ ushort lds[LDS_U];

    const int tid  = threadIdx.x;
    const int w    = tid >> 6;
    const int lane = tid & 63;
    const int c    = lane & 15;           // query column within wave's 16
    const int g    = lane >> 4;           // k-chunk
    // XCD-aware bijective swizzle (512 % 8 == 0): 2 heads per XCD
    const int bid  = blockIdx.x;
    const int swz  = (bid & 7) * 64 + (bid >> 3);
    const int h    = swz >> 5;
    const int n0   = (swz & 31) << 6;

    const float* __restrict__ qh = q + (size_t)(h * S) * D;
    const float* __restrict__ kh = k + (size_t)(h * S) * D;
    const float* __restrict__ vh = v + (size_t)(h * S) * D;

    // ---- V prefetch into regs (issue-early). 640 tasks: 2 rows x 8 dims each.
    const int ntask = (tid < 128) ? 3 : 2;
    float4 vreg[3][4];
#pragma unroll
    for (int tt = 0; tt < 3; ++tt) {
        if (tt < ntask) {
            const int tau = tid + (tt << 8);
            const int rp = tau % 80, ch = tau / 80;
            const float* s0 = vh + (size_t)rowpos(2 * rp,     n0) * D + ch * 8;
            const float* s1 = vh + (size_t)rowpos(2 * rp + 1, n0) * D + ch * 8;
            vreg[tt][0] = *(const float4*)s0;
            vreg[tt][1] = *(const float4*)(s0 + 4);
            vreg[tt][2] = *(const float4*)s1;
            vreg[tt][3] = *(const float4*)(s1 + 4);
        }
    }

    // ---- Q direct load (issue-early); hi/lo convert into B-operand frags ----
    const int qb = w * 16;
    const int qi = qb + c;                // this lane's block-relative query
    const int nq = n0 + qi;
    const float* qrow = qh + (size_t)(n0 + qb + c) * D;
    const float4 qv00 = *(const float4*)(qrow + g * 8);
    const float4 qv01 = *(const float4*)(qrow + g * 8 + 4);
    const float4 qv10 = *(const float4*)(qrow + 32 + g * 8);
    const float4 qv11 = *(const float4*)(qrow + 32 + g * 8 + 4);

    // ---- K staging (coalesced): 1280 tasks of 8 dims, 5 iters exact ----
    for (int t = tid; t < 1280; t += 256) {
        const int row = t >> 3, ch = t & 7;
        const float* src = kh + (size_t)rowpos(row, n0) * D + ch * 8;
        const float4 a = *(const float4*)src;
        const float4 b = *(const float4*)(src + 4);
        *(bf16x8*)&lds[KB + row * KSTRIDE + ch * 8] = cvt8(a, b);
    }

    // ---- Q frag convert (overlaps K-staging latency) ----
    bf16x8 bQH0, bQL0, bQH1, bQL1;
    cvt_hilo(qv00, qv01, bQH0, bQL0);
    cvt_hilo(qv10, qv11, bQH1, bQL1);

    // ---- V pack + V^T write (dedicated region, pre-barrier) ----
    // key 32kt+16u+4g2+jj -> slot 32kt+8g2+4u+jj (same k-permutation as pa pack)
#pragma unroll
    for (int tt = 0; tt < 3; ++tt) {
        if (tt < ntask) {
            const int tau = tid + (tt << 8);
            const int rp = tau % 80, ch = tau / 80;
            const float r0[8] = {vreg[tt][0].x, vreg[tt][0].y, vreg[tt][0].z, vreg[tt][0].w,
                                 vreg[tt][1].x, vreg[tt][1].y, vreg[tt][1].z, vreg[tt][1].w};
            const float r1[8] = {vreg[tt][2].x, vreg[tt][2].y, vreg[tt][2].z, vreg[tt][2].w,
                                 vreg[tt][3].x, vreg[tt][3].y, vreg[tt][3].z, vreg[tt][3].w};
            const int kk = 2 * rp;
            const int kt = kk >> 5, rem = kk & 31;
            const int slot = kt * 32 + ((rem >> 2) & 3) * 8 + (rem >> 4) * 4 + (rem & 3);
#pragma unroll
            for (int j = 0; j < 8; ++j)
                *(unsigned*)&lds[VTB + (ch * 8 + j) * VSTR + slot] = pk2(r0[j], r1[j]);
        }
    }

    __syncthreads();   // the ONLY barrier: K + V^T visible to all waves

    // ---- QK^T swapped (S^T = K·Q^T): wave w, 16 queries x all 160 keys ----
    f32x4 acc[NT];
#pragma unroll
    for (int t = 0; t < NT; ++t) acc[t] = (f32x4){0.f, 0.f, 0.f, 0.f};
#pragma unroll
    for (int t = 0; t < NT; ++t) {
        const int kb = KB + (t * 16 + c) * KSTRIDE + g * 8;
        const bf16x8 a0 = *(bf16x8*)&lds[kb];
        const bf16x8 a1 = *(bf16x8*)&lds[kb + 32];
        f32x4 a4 = acc[t];
        a4 = __builtin_amdgcn_mfma_f32_16x16x32_bf16(a0, bQH0, a4, 0, 0, 0);
        a4 = __builtin_amdgcn_mfma_f32_16x16x32_bf16(a1, bQH1, a4, 0, 0, 0);
        a4 = __builtin_amdgcn_mfma_f32_16x16x32_bf16(a0, bQL0, a4, 0, 0, 0);
        a4 = __builtin_amdgcn_mfma_f32_16x16x32_bf16(a1, bQL1, a4, 0, 0, 0);
        acc[t] = a4;
    }

    // ---- softmax fully in-lane (exp2 domain): lane holds keys {16t+4g+i} ----
    float p[NT][4];
#pragma unroll
    for (int t = 0; t < 6; ++t) {
#pragma unroll
        for (int i = 0; i < 4; ++i) {
            const int j = t * 16 + 4 * g + i;
            const bool ok = ((unsigned)(j - qi) <= 32u) &&
                            ((unsigned)(n0 - W + j) < (unsigned)S);
            p[t][i] = ok ? acc[t][i] * S2 : -INFINITY;
        }
    }
    const bool us = nq > W;
#pragma unroll
    for (int t = 6; t < NT; ++t)
#pragma unroll
        for (int i = 0; i < 4; ++i)
            p[t][i] = us ? acc[t][i] * S2 : -INFINITY;

    float m = -INFINITY;
#pragma unroll
    for (int t = 0; t < NT; ++t)
#pragma unroll
        for (int i = 0; i < 4; ++i) m = fmaxf(m, p[t][i]);
    m = fmaxf(m, __shfl_xor(m, 16));
    m = fmaxf(m, __shfl_xor(m, 32));     // finite: self-key always valid

    float l = 0.f;
#pragma unroll
    for (int t = 0; t < NT; ++t)
#pragma unroll
        for (int i = 0; i < 4; ++i) { p[t][i] = exp2f(p[t][i] - m); l += p[t][i]; }
    l += __shfl_xor(l, 16);
    l += __shfl_xor(l, 32);
    const float inv = 1.0f / l;

    // ---- pack P into PV A-frags in-register (k-permutation shared with V^T) ----
    union { bf16x8 v; unsigned u[4]; } pa[5];
#pragma unroll
    for (int kt = 0; kt < 5; ++kt) {
        pa[kt].u[0] = pk2(p[2 * kt][0] * inv,     p[2 * kt][1] * inv);
        pa[kt].u[1] = pk2(p[2 * kt][2] * inv,     p[2 * kt][3] * inv);
        pa[kt].u[2] = pk2(p[2 * kt + 1][0] * inv, p[2 * kt + 1][1] * inv);
        pa[kt].u[3] = pk2(p[2 * kt + 1][2] * inv, p[2 * kt + 1][3] * inv);
    }

    // ---- PV: o[q][d] = P(16x160) x V(160x64); A = pa (in-reg), B = V^T ----
    f32x4 o[4];
#pragma unroll
    for (int dt = 0; dt < 4; ++dt) o[dt] = (f32x4){0.f, 0.f, 0.f, 0.f};
#pragma unroll
    for (int kt = 0; kt < 5; ++kt) {
#pragma unroll
        for (int dt = 0; dt < 4; ++dt) {
            const bf16x8 vb = *(bf16x8*)&lds[VTB + (dt * 16 + c) * VSTR + kt * 32 + g * 8];
            o[dt] = __builtin_amdgcn_mfma_f32_16x16x32_bf16(pa[kt].v, vb, o[dt], 0, 0, 0);
        }
    }

    // ---- store (D row = query qb+4g+i, col c = dim within tile; P pre-normalized)
#pragma unroll
    for (int i = 0; i < 4; ++i) {
        const int n = n0 + qb + 4 * g + i;
        float* op = out + ((size_t)(h * S) + n) * D + c;
#pragma unroll
        for (int dt = 0; dt < 4; ++dt) op[dt * 16] = o[dt][i];
    }
}

extern "C" void kernel_launch(void* const* d_in, const int* in_sizes, int n_in,
                              void* d_out, int out_size, void* d_ws, size_t ws_size,
                              hipStream_t stream) {
    (void)in_sizes; (void)n_in; (void)d_ws; (void)ws_size; (void)out_size;
    const float* q = (const float*)d_in[0];
    const float* k = (const float*)d_in[1];
    const float* v = (const float*)d_in[2];
    float* out     = (float*)d_out;

    dim3 grid(H * (S / QB));   // 512 blocks
    dim3 block(256);
    strided_attn_mfma<<<grid, block, 0, stream>>>(q, k, v, out);
}